// Round 7
// baseline (3978.372 us; speedup 1.0000x reference)
//
#include <hip/hip_runtime.h>
#include <hip/hip_cooperative_groups.h>

namespace cg = cooperative_groups;

#define VIEWS 360
#define NDET 736
#define NX 512
#define NY 512
#define NPIX (NX * NY)

typedef unsigned short u16;
typedef __attribute__((ext_vector_type(8))) short bf16x8;
typedef __attribute__((ext_vector_type(4))) float f32x4;

__device__ __forceinline__ u16 f2bf(float f) {
  unsigned u = __float_as_uint(f);
  return (u16)((u + 0x7fffu + ((u >> 16) & 1u)) >> 16);
}

// ---------------------------------------------------------------------------
// Fused linear1+linear2, 4 views/block. h1 kept in LDS (bit-identical to the
// global round-trip). Each thread owns 3 d-rows x 4 views per layer.
// ---------------------------------------------------------------------------
__global__ __launch_bounds__(256) void linear2_kernel(
    const float* __restrict__ x, const float* __restrict__ w1,
    const float* __restrict__ b1, const float* __restrict__ w2,
    const float* __restrict__ b2, float* __restrict__ out) {
  __shared__ __align__(16) float xin[4][NDET];
  __shared__ __align__(16) float h1s[4][NDET];
  const int v0 = blockIdx.x * 4;
  const int t = threadIdx.x;
  for (int k = t; k < 4 * (NDET / 4); k += 256) {
    const int row = k / (NDET / 4), c4 = k % (NDET / 4);
    ((float4*)xin[row])[c4] =
        ((const float4*)(x + (size_t)(v0 + row) * NDET))[c4];
  }
  __syncthreads();

  const bool has2 = (t < NDET - 512);  // t < 224

#pragma unroll 1
  for (int L = 0; L < 2; ++L) {
    const float* w = L ? w2 : w1;
    const float* b = L ? b2 : b1;
    const float(*src)[NDET] = L ? h1s : xin;

    const float4* w0 = (const float4*)(w + (size_t)t * NDET);
    const float4* w1p = (const float4*)(w + (size_t)(t + 256) * NDET);
    const float4* w2p = (const float4*)(w + (size_t)(has2 ? t + 512 : t) * NDET);

    float acc[3][4];
#pragma unroll
    for (int j = 0; j < 3; ++j)
#pragma unroll
      for (int v = 0; v < 4; ++v) acc[j][v] = 0.f;

#pragma unroll 2
    for (int k = 0; k < NDET / 4; ++k) {
      float4 xv0 = ((const float4*)src[0])[k];
      float4 xv1 = ((const float4*)src[1])[k];
      float4 xv2 = ((const float4*)src[2])[k];
      float4 xv3 = ((const float4*)src[3])[k];
      float4 wv;
      wv = w0[k];
      acc[0][0] = fmaf(xv0.x, wv.x, fmaf(xv0.y, wv.y, fmaf(xv0.z, wv.z, fmaf(xv0.w, wv.w, acc[0][0]))));
      acc[0][1] = fmaf(xv1.x, wv.x, fmaf(xv1.y, wv.y, fmaf(xv1.z, wv.z, fmaf(xv1.w, wv.w, acc[0][1]))));
      acc[0][2] = fmaf(xv2.x, wv.x, fmaf(xv2.y, wv.y, fmaf(xv2.z, wv.z, fmaf(xv2.w, wv.w, acc[0][2]))));
      acc[0][3] = fmaf(xv3.x, wv.x, fmaf(xv3.y, wv.y, fmaf(xv3.z, wv.z, fmaf(xv3.w, wv.w, acc[0][3]))));
      wv = w1p[k];
      acc[1][0] = fmaf(xv0.x, wv.x, fmaf(xv0.y, wv.y, fmaf(xv0.z, wv.z, fmaf(xv0.w, wv.w, acc[1][0]))));
      acc[1][1] = fmaf(xv1.x, wv.x, fmaf(xv1.y, wv.y, fmaf(xv1.z, wv.z, fmaf(xv1.w, wv.w, acc[1][1]))));
      acc[1][2] = fmaf(xv2.x, wv.x, fmaf(xv2.y, wv.y, fmaf(xv2.z, wv.z, fmaf(xv2.w, wv.w, acc[1][2]))));
      acc[1][3] = fmaf(xv3.x, wv.x, fmaf(xv3.y, wv.y, fmaf(xv3.z, wv.z, fmaf(xv3.w, wv.w, acc[1][3]))));
      wv = w2p[k];
      acc[2][0] = fmaf(xv0.x, wv.x, fmaf(xv0.y, wv.y, fmaf(xv0.z, wv.z, fmaf(xv0.w, wv.w, acc[2][0]))));
      acc[2][1] = fmaf(xv1.x, wv.x, fmaf(xv1.y, wv.y, fmaf(xv1.z, wv.z, fmaf(xv1.w, wv.w, acc[2][1]))));
      acc[2][2] = fmaf(xv2.x, wv.x, fmaf(xv2.y, wv.y, fmaf(xv2.z, wv.z, fmaf(xv2.w, wv.w, acc[2][2]))));
      acc[2][3] = fmaf(xv3.x, wv.x, fmaf(xv3.y, wv.y, fmaf(xv3.z, wv.z, fmaf(xv3.w, wv.w, acc[2][3]))));
    }

    const float b0 = b[t], b1v = b[t + 256];
    const float b2v = has2 ? b[t + 512] : 0.f;
    if (L == 0) {
#pragma unroll
      for (int v = 0; v < 4; ++v) {
        h1s[v][t] = fmaxf(acc[0][v] + b0, 0.f);
        h1s[v][t + 256] = fmaxf(acc[1][v] + b1v, 0.f);
        if (has2) h1s[v][t + 512] = fmaxf(acc[2][v] + b2v, 0.f);
      }
      __syncthreads();
    } else {
#pragma unroll
      for (int v = 0; v < 4; ++v) {
        float* o = out + (size_t)(v0 + v) * NDET;
        o[t] = fmaxf(acc[0][v] + b0, 0.f);
        o[t + 256] = fmaxf(acc[1][v] + b1v, 0.f);
        if (has2) o[t + 512] = fmaxf(acc[2][v] + b2v, 0.f);
      }
    }
  }
}

// ---------------------------------------------------------------------------
// Backprojection: thread-owns-pixel + idx coalesced via LDS staging of
// 72-view chunks. Row pad 77 dwords -> conflict-free LDS reads.
// ---------------------------------------------------------------------------
__global__ __launch_bounds__(256) void backproj_kernel(
    const float* __restrict__ sino, const int* __restrict__ idx,
    float* __restrict__ img) {
  __shared__ int lidx[256 * 77];
  const int t = threadIdx.x;
  const int p_base = blockIdx.x * 256;

  float a0 = 0.f, a1 = 0.f, a2 = 0.f, a3 = 0.f;

#pragma unroll 1
  for (int c = 0; c < 5; ++c) {
    if (c) __syncthreads();
#pragma unroll
    for (int k = 0; k < 18; ++k) {
      const int f = k * 256 + t;
      const int row = f / 18, col4 = f % 18;
      int4 v = *(const int4*)&idx[(size_t)(p_base + row) * VIEWS + c * 72 +
                                  col4 * 4];
      int* dst = &lidx[row * 77 + col4 * 4];
      dst[0] = v.x; dst[1] = v.y; dst[2] = v.z; dst[3] = v.w;
    }
    __syncthreads();
    const int* myrow = &lidx[t * 77];
#pragma unroll
    for (int j = 0; j < 72; j += 4) {
      a0 += sino[myrow[j + 0]];
      a1 += sino[myrow[j + 1]];
      a2 += sino[myrow[j + 2]];
      a3 += sino[myrow[j + 3]];
    }
  }

  const int p = p_base + t;
  const int ix = p >> 9, iy = p & 511;
  img[(NX - 1 - ix) * NY + (NY - 1 - iy)] =
      ((a0 + a1) + (a2 + a3)) * 0.00872665f;  // END_ANGLE / (2*VIEWS)
}

// ---------------------------------------------------------------------------
// fp32 3x3 neighborhood load (zero pad), single plane
// ---------------------------------------------------------------------------
__device__ __forceinline__ void load9(const float* __restrict__ base, int gx,
                                      int gy, float v[9]) {
  const bool xm = gx > 0, xp = gx < NX - 1, ym = gy > 0, yp = gy < NY - 1;
  const float* c = base + gy * NX + gx;
  v[0] = (ym && xm) ? c[-NX - 1] : 0.f;
  v[1] = (ym)       ? c[-NX]     : 0.f;
  v[2] = (ym && xp) ? c[-NX + 1] : 0.f;
  v[3] = (xm)       ? c[-1]      : 0.f;
  v[4] =               c[0];
  v[5] = (xp)       ? c[1]       : 0.f;
  v[6] = (yp && xm) ? c[NX - 1]  : 0.f;
  v[7] = (yp)       ? c[NX]      : 0.f;
  v[8] = (yp && xp) ? c[NX + 1]  : 0.f;
}

__device__ __forceinline__ float dot9(float a, const float v[9],
                                      const float* __restrict__ w) {
  a = fmaf(v[0], w[0], a);
  a = fmaf(v[1], w[1], a);
  a = fmaf(v[2], w[2], a);
  a = fmaf(v[3], w[3], a);
  a = fmaf(v[4], w[4], a);
  a = fmaf(v[5], w[5], a);
  a = fmaf(v[6], w[6], a);
  a = fmaf(v[7], w[7], a);
  a = fmaf(v[8], w[8], a);
  return a;
}

// ---------------------------------------------------------------------------
// conv_in (fallback path): 1 -> 64 channels, fp32 plane -> fp32 NHWC.
// ---------------------------------------------------------------------------
__global__ __launch_bounds__(256) void conv_in_kernel(
    const float* __restrict__ in, const float* __restrict__ w,
    const float* __restrict__ b, float* __restrict__ out) {
  const int p = blockIdx.x * 256 + threadIdx.x;
  const int gx = p & (NX - 1), gy = p >> 9;
  float v[9];
  load9(in, gx, gy, v);
  float4* o = (float4*)(out + (size_t)p * 64);
#pragma unroll
  for (int oq = 0; oq < 16; ++oq) {
    float4 r;
    r.x = fmaxf(dot9(b[oq * 4 + 0], v, w + (oq * 4 + 0) * 9), 0.f);
    r.y = fmaxf(dot9(b[oq * 4 + 1], v, w + (oq * 4 + 1) * 9), 0.f);
    r.z = fmaxf(dot9(b[oq * 4 + 2], v, w + (oq * 4 + 2) * 9), 0.f);
    r.w = fmaxf(dot9(b[oq * 4 + 3], v, w + (oq * 4 + 3) * 9), 0.f);
    o[oq] = r;
  }
}

// ---------------------------------------------------------------------------
// Weight prep -> per-(step,mf)-contiguous layout:
//   wR[li][s][mf][lane][j] = W[li][oc=mf*16+(lane&15)][ic=kb*32+(lane>>4)*8+j][tap]
// with s = kb*9 + tap (kb-major).
// ---------------------------------------------------------------------------
__global__ __launch_bounds__(256) void prep_weights_kernel(
    const float* __restrict__ bw1, const float* __restrict__ bw2,
    u16* __restrict__ wR) {
  const int g = blockIdx.x * 256 + threadIdx.x;
  if (g >= 22 * 36864) return;
  const int li = g / 36864, r1 = g % 36864;
  const int s = r1 / 2048, r2 = r1 % 2048;
  const int mf = r2 / 512, r3 = r2 % 512;
  const int lane = r3 / 8, j = r3 % 8;
  const int kb = s / 9, tap = s % 9;  // kb-major step order
  const int kg = lane >> 4, n = lane & 15;
  const int oc = mf * 16 + n;
  const int ic = kb * 32 + kg * 8 + j;
  const float* src = (li < 11) ? bw1 + li * 36864 : bw2 + (li - 11) * 36864;
  wR[g] = f2bf(src[(oc * 64 + ic) * 9 + tap]);
}

// ---------------------------------------------------------------------------
// One conv64 layer body for tile (xb,yb): K-split LDS staging + MFMA + direct
// epilogue. Shared by the coop kernel and the fallback kernel.
// ---------------------------------------------------------------------------
__device__ __forceinline__ void conv64_tile(
    const void* in_, const u16* wA, const float* bias, const float* res,
    void* out_, u16* lds, int xb, int yb, int tid, int sub) {
  const int wv = tid >> 6;
  const int lane = tid & 63;
  const int n = lane & 15;
  const int kg = lane >> 4;

  f32x4 acc[4][4];
#pragma unroll
  for (int i = 0; i < 4; ++i)
#pragma unroll
    for (int j = 0; j < 4; ++j) acc[i][j] = (f32x4){0.f, 0.f, 0.f, 0.f};

#pragma unroll 1
  for (int kb = 0; kb < 2; ++kb) {
    __syncthreads();  // protect LDS reuse (prev half / prev tile / prev layer)
    // stage one 32-ch half: 6 rows x 66 xi x 4 chunks = 1584 uint4
#pragma unroll
    for (int it = 0; it < 7; ++it) {
      const int g = it * 256 + tid;
      if (g < 1584) {
        const int icq = g & 3;
        const int xr = g >> 2;
        const int x66 = xr % 66;
        const int r = xr / 66;
        const int y = yb - 1 + r;
        const int x = xb - 1 + x66;
        uint4 d = {0u, 0u, 0u, 0u};
        if ((unsigned)y < 512u && (unsigned)x < 512u) {
          const size_t gi = ((size_t)((y << 9) + x)) * 64 + kb * 32 + icq * 8;
          if (sub) {
            d = *(const uint4*)&((const u16*)in_)[gi];
          } else {
            const float* s = &((const float*)in_)[gi];
            float4 f0 = *(const float4*)s;
            float4 f1 = *(const float4*)(s + 4);
            d.x = (unsigned)f2bf(f0.x) | ((unsigned)f2bf(f0.y) << 16);
            d.y = (unsigned)f2bf(f0.z) | ((unsigned)f2bf(f0.w) << 16);
            d.z = (unsigned)f2bf(f1.x) | ((unsigned)f2bf(f1.y) << 16);
            d.w = (unsigned)f2bf(f1.z) | ((unsigned)f2bf(f1.w) << 16);
          }
        }
        const int slot = icq ^ ((x66 >> 1) & 3);
        *(uint4*)&lds[(xr * 4 + slot) * 8] = d;
      }
    }
    __syncthreads();

#pragma unroll 3
    for (int tap = 0; tap < 9; ++tap) {
      const int s = kb * 9 + tap;
      bf16x8 av[4];
#pragma unroll
      for (int mf = 0; mf < 4; ++mf)
        av[mf] = *(const bf16x8*)&wA[(size_t)s * 2048 + mf * 512 + lane * 8];

      const int r = wv + tap / 3;
      const int dxp1 = tap % 3;

      bf16x8 bfr[4];
#pragma unroll
      for (int nf = 0; nf < 4; ++nf) {
        const int xi = dxp1 + nf * 16 + n;
        const int slot = kg ^ ((xi >> 1) & 3);
        bfr[nf] = *(const bf16x8*)&lds[((r * 66 + xi) * 4 + slot) * 8];
      }
#pragma unroll
      for (int mf = 0; mf < 4; ++mf)
#pragma unroll
        for (int nf = 0; nf < 4; ++nf)
          acc[mf][nf] = __builtin_amdgcn_mfma_f32_16x16x32_bf16(
              av[mf], bfr[nf], acc[mf][nf], 0, 0, 0);
    }
  }

  const int y = yb + wv;
#pragma unroll
  for (int mf = 0; mf < 4; ++mf) {
    const float4 bv = *(const float4*)&bias[mf * 16 + kg * 4];
#pragma unroll
    for (int nf = 0; nf < 4; ++nf) {
      const int x = xb + nf * 16 + n;
      const size_t base = ((size_t)((y << 9) + x)) * 64 + mf * 16 + kg * 4;
      float v0 = acc[mf][nf][0] + bv.x;
      float v1 = acc[mf][nf][1] + bv.y;
      float v2 = acc[mf][nf][2] + bv.z;
      float v3 = acc[mf][nf][3] + bv.w;
      if (sub) {
        float4 rr = *(const float4*)&res[base];
        v0 += rr.x; v1 += rr.y; v2 += rr.z; v3 += rr.w;
        v0 = fmaxf(v0, 0.f); v1 = fmaxf(v1, 0.f);
        v2 = fmaxf(v2, 0.f); v3 = fmaxf(v3, 0.f);
        *(float4*)&((float*)out_)[base] = (float4){v0, v1, v2, v3};
      } else {
        v0 = fmaxf(v0, 0.f); v1 = fmaxf(v1, 0.f);
        v2 = fmaxf(v2, 0.f); v3 = fmaxf(v3, 0.f);
        uint2 pk;
        pk.x = (unsigned)f2bf(v0) | ((unsigned)f2bf(v1) << 16);
        pk.y = (unsigned)f2bf(v2) | ((unsigned)f2bf(v3) << 16);
        *(uint2*)&((u16*)out_)[base] = pk;
      }
    }
  }
}

// ---------------------------------------------------------------------------
// Fallback per-layer conv64 kernel (proven R4 path).
// ---------------------------------------------------------------------------
template <int SUB>
__global__ __launch_bounds__(256, 4) void conv64_mfma(
    const void* __restrict__ in_, const u16* __restrict__ wA,
    const float* __restrict__ bias, const float* __restrict__ res,
    void* __restrict__ out_) {
  __shared__ __align__(16) u16 lds[6 * 66 * 32];
  const int xb = (blockIdx.x & 7) * 64;
  const int yb = (int)(blockIdx.x >> 3) * 4;
  conv64_tile(in_, wA, bias, res, out_, lds, xb, yb, threadIdx.x, SUB);
}

// ---------------------------------------------------------------------------
// conv_out (fallback path): 64 -> 1, fp32 NHWC in, fp32 plane out.
// ---------------------------------------------------------------------------
__global__ __launch_bounds__(256) void conv_out_kernel(
    const float* __restrict__ in, const float* __restrict__ w,
    const float* __restrict__ b, float* __restrict__ out) {
  const int p = blockIdx.x * 256 + threadIdx.x;
  const int gx = p & (NX - 1), gy = p >> 9;
  float a = b[0];
#pragma unroll
  for (int ty = 0; ty < 3; ++ty) {
#pragma unroll
    for (int tx = 0; tx < 3; ++tx) {
      const int yy = gy + ty - 1, xx = gx + tx - 1;
      if ((unsigned)yy < 512u && (unsigned)xx < 512u) {
        const float4* q = (const float4*)(in + ((size_t)((yy << 9) + xx)) * 64);
        const int tap = ty * 3 + tx;
#pragma unroll
        for (int i = 0; i < 16; ++i) {
          float4 d = q[i];
          a = fmaf(d.x, w[(i * 4 + 0) * 9 + tap], a);
          a = fmaf(d.y, w[(i * 4 + 1) * 9 + tap], a);
          a = fmaf(d.z, w[(i * 4 + 2) * 9 + tap], a);
          a = fmaf(d.w, w[(i * 4 + 3) * 9 + tap], a);
        }
      }
    }
  }
  out[p] = a;
}

// ---------------------------------------------------------------------------
// COOPERATIVE conv stack, PERSISTENT tiles: grid sized by the occupancy API
// at launch (any size >= 1 works); each block loops tile += gridDim.x over
// the 1024 (64x4) tiles per stage. 23 grid.sync()s replace 23 launch
// boundaries. Per-tile body identical to the fallback path.
// ---------------------------------------------------------------------------
__global__ __launch_bounds__(256, 4) void conv_coop(
    const float* __restrict__ img, const float* __restrict__ cin_w,
    const float* __restrict__ cin_b, const u16* __restrict__ wAll,
    const float* __restrict__ bb1, const float* __restrict__ bb2,
    const float* __restrict__ cout_w, const float* __restrict__ cout_b,
    float* __restrict__ yf, u16* __restrict__ zb,
    float* __restrict__ outp) {
  cg::grid_group grid = cg::this_grid();
  __shared__ __align__(16) u16 lds[6 * 66 * 32];  // 25,344 B
  const int tid = threadIdx.x;
  const int G = gridDim.x;

  // ---- conv_in over owned tiles ----
  for (int tile = blockIdx.x; tile < 1024; tile += G) {
    const int xb = (tile & 7) * 64, yb = (tile >> 3) * 4;
    const int gx = xb + (tid & 63);
    const int gy = yb + (tid >> 6);
    float v[9];
    load9(img, gx, gy, v);
    float4* o = (float4*)(yf + ((size_t)((gy << 9) + gx)) * 64);
#pragma unroll
    for (int oq = 0; oq < 16; ++oq) {
      float4 r;
      r.x = fmaxf(dot9(cin_b[oq * 4 + 0], v, cin_w + (oq * 4 + 0) * 9), 0.f);
      r.y = fmaxf(dot9(cin_b[oq * 4 + 1], v, cin_w + (oq * 4 + 1) * 9), 0.f);
      r.z = fmaxf(dot9(cin_b[oq * 4 + 2], v, cin_w + (oq * 4 + 2) * 9), 0.f);
      r.w = fmaxf(dot9(cin_b[oq * 4 + 3], v, cin_w + (oq * 4 + 3) * 9), 0.f);
      o[oq] = r;
    }
  }
  grid.sync();

  // ---- 22 conv layers ----
#pragma unroll 1
  for (int li = 0; li < 22; ++li) {
    const int sub = li & 1;   // 0: conv1 (yf->zb), 1: conv2 (zb->yf+res)
    const int blk = li >> 1;
    const u16* wA = wAll + (size_t)(sub ? 11 + blk : blk) * 36864;
    const float* bias = (sub ? bb2 : bb1) + blk * 64;

    for (int tile = blockIdx.x; tile < 1024; tile += G) {
      const int xb = (tile & 7) * 64, yb = (tile >> 3) * 4;
      if (sub)
        conv64_tile(zb, wA, bias, yf, yf, lds, xb, yb, tid, 1);
      else
        conv64_tile(yf, wA, bias, nullptr, zb, lds, xb, yb, tid, 0);
    }
    grid.sync();
  }

  // ---- conv_out over owned tiles ----
  for (int tile = blockIdx.x; tile < 1024; tile += G) {
    const int xb = (tile & 7) * 64, yb = (tile >> 3) * 4;
    const int gx = xb + (tid & 63);
    const int gy = yb + (tid >> 6);
    float a = cout_b[0];
#pragma unroll
    for (int ty = 0; ty < 3; ++ty) {
#pragma unroll
      for (int tx = 0; tx < 3; ++tx) {
        const int yy = gy + ty - 1, xx = gx + tx - 1;
        if ((unsigned)yy < 512u && (unsigned)xx < 512u) {
          const float4* q =
              (const float4*)(yf + ((size_t)((yy << 9) + xx)) * 64);
          const int tap = ty * 3 + tx;
#pragma unroll
          for (int i = 0; i < 16; ++i) {
            float4 d = q[i];
            a = fmaf(d.x, cout_w[(i * 4 + 0) * 9 + tap], a);
            a = fmaf(d.y, cout_w[(i * 4 + 1) * 9 + tap], a);
            a = fmaf(d.z, cout_w[(i * 4 + 2) * 9 + tap], a);
            a = fmaf(d.w, cout_w[(i * 4 + 3) * 9 + tap], a);
          }
        }
      }
    }
    outp[(gy << 9) + gx] = a;
  }
}

// ---------------------------------------------------------------------------
extern "C" void kernel_launch(void* const* d_in, const int* in_sizes, int n_in,
                              void* d_out, int out_size, void* d_ws,
                              size_t ws_size, hipStream_t stream) {
  const float* x      = (const float*)d_in[0];
  const int*   indices= (const int*)d_in[1];
  const float* w1     = (const float*)d_in[2];
  const float* b1     = (const float*)d_in[3];
  const float* w2     = (const float*)d_in[4];
  const float* b2     = (const float*)d_in[5];
  const float* cin_w  = (const float*)d_in[6];
  const float* cin_b  = (const float*)d_in[7];
  const float* bw1    = (const float*)d_in[8];
  const float* bb1    = (const float*)d_in[9];
  const float* bw2    = (const float*)d_in[10];
  const float* bb2    = (const float*)d_in[11];
  const float* cout_w = (const float*)d_in[12];
  const float* cout_b = (const float*)d_in[13];

  float* ws   = (float*)d_ws;
  float* h2   = ws;                        // 360*736 f32
  float* img  = h2 + VIEWS * NDET;         // NPIX f32 (plane)
  float* yf   = img + NPIX;                // 64*NPIX f32 NHWC (trunk)
  u16*  zb    = (u16*)(yf + (size_t)64 * NPIX);  // 64*NPIX bf16 NHWC
  u16*  wAll  = zb + (size_t)64 * NPIX;    // 22*64*576 bf16 (step,mf layout)

  prep_weights_kernel<<<(22 * 36864 + 255) / 256, 256, 0, stream>>>(bw1, bw2,
                                                                    wAll);
  linear2_kernel<<<VIEWS / 4, 256, 0, stream>>>(x, w1, b1, w2, b2, h2);
  backproj_kernel<<<NPIX / 256, 256, 0, stream>>>(h2, indices, img);

  float* outp = (float*)d_out;

  // Cooperative path: grid sized by achieved occupancy (cached).
  static int coop_grid = -2;  // -2 uncomputed, -1 unavailable
  if (coop_grid == -2) {
    int bpcu = 0;
    hipError_t e = hipOccupancyMaxActiveBlocksPerMultiprocessor(
        &bpcu, (const void*)conv_coop, 256, 0);
    coop_grid = (e == hipSuccess && bpcu > 0)
                    ? ((bpcu * 256 < 1024) ? bpcu * 256 : 1024)
                    : -1;
  }

  bool done = false;
  if (coop_grid > 0) {
    void* cargs[] = {&img,    &cin_w,  &cin_b, &wAll, &bb1, &bb2,
                     &cout_w, &cout_b, &yf,    &zb,   &outp};
    hipError_t err = hipLaunchCooperativeKernel(
        (const void*)conv_coop, dim3(coop_grid), dim3(256), cargs, 0, stream);
    if (err == hipSuccess) {
      done = true;
    } else {
      (void)hipGetLastError();  // clear sticky error
      coop_grid = -1;           // don't retry
    }
  }

  if (!done) {
    // Proven per-layer fallback (R4 path).
    conv_in_kernel<<<NPIX / 256, 256, 0, stream>>>(img, cin_w, cin_b, yf);
    for (int i = 0; i < 11; ++i) {
      conv64_mfma<0><<<1024, 256, 0, stream>>>(
          yf, wAll + i * 36864, bb1 + i * 64, nullptr, zb);
      conv64_mfma<1><<<1024, 256, 0, stream>>>(
          zb, wAll + (11 + i) * 36864, bb2 + i * 64, yf, yf);
    }
    conv_out_kernel<<<NPIX / 256, 256, 0, stream>>>(yf, cout_w, cout_b, outp);
  }
}

// Round 8
// 1954.827 us; speedup vs baseline: 2.0352x; 2.0352x over previous
//
#include <hip/hip_runtime.h>

#define VIEWS 360
#define NDET 736
#define NX 512
#define NY 512
#define NPIX (NX * NY)

typedef unsigned short u16;
typedef __attribute__((ext_vector_type(8))) short bf16x8;
typedef __attribute__((ext_vector_type(4))) float f32x4;

// Fused "make my LDS writes visible + barrier" WITHOUT the vmcnt(0) drain
// that __syncthreads() emits -- keeps prefetch global loads in flight
// across the barrier (HK pattern; guide §5).
#define BAR_LDS() asm volatile("s_waitcnt lgkmcnt(0)\n\ts_barrier" ::: "memory")

__device__ __forceinline__ u16 f2bf(float f) {
  unsigned u = __float_as_uint(f);
  return (u16)((u + 0x7fffu + ((u >> 16) & 1u)) >> 16);
}

// ---------------------------------------------------------------------------
// Fused linear1+linear2, 4 views/block. h1 kept in LDS (bit-identical to the
// global round-trip). Each thread owns 3 d-rows x 4 views per layer.
// ---------------------------------------------------------------------------
__global__ __launch_bounds__(256) void linear2_kernel(
    const float* __restrict__ x, const float* __restrict__ w1,
    const float* __restrict__ b1, const float* __restrict__ w2,
    const float* __restrict__ b2, float* __restrict__ out) {
  __shared__ __align__(16) float xin[4][NDET];
  __shared__ __align__(16) float h1s[4][NDET];
  const int v0 = blockIdx.x * 4;
  const int t = threadIdx.x;
  for (int k = t; k < 4 * (NDET / 4); k += 256) {
    const int row = k / (NDET / 4), c4 = k % (NDET / 4);
    ((float4*)xin[row])[c4] =
        ((const float4*)(x + (size_t)(v0 + row) * NDET))[c4];
  }
  __syncthreads();

  const bool has2 = (t < NDET - 512);  // t < 224

#pragma unroll 1
  for (int L = 0; L < 2; ++L) {
    const float* w = L ? w2 : w1;
    const float* b = L ? b2 : b1;
    const float(*src)[NDET] = L ? h1s : xin;

    const float4* w0 = (const float4*)(w + (size_t)t * NDET);
    const float4* w1p = (const float4*)(w + (size_t)(t + 256) * NDET);
    const float4* w2p = (const float4*)(w + (size_t)(has2 ? t + 512 : t) * NDET);

    float acc[3][4];
#pragma unroll
    for (int j = 0; j < 3; ++j)
#pragma unroll
      for (int v = 0; v < 4; ++v) acc[j][v] = 0.f;

#pragma unroll 2
    for (int k = 0; k < NDET / 4; ++k) {
      float4 xv0 = ((const float4*)src[0])[k];
      float4 xv1 = ((const float4*)src[1])[k];
      float4 xv2 = ((const float4*)src[2])[k];
      float4 xv3 = ((const float4*)src[3])[k];
      float4 wv;
      wv = w0[k];
      acc[0][0] = fmaf(xv0.x, wv.x, fmaf(xv0.y, wv.y, fmaf(xv0.z, wv.z, fmaf(xv0.w, wv.w, acc[0][0]))));
      acc[0][1] = fmaf(xv1.x, wv.x, fmaf(xv1.y, wv.y, fmaf(xv1.z, wv.z, fmaf(xv1.w, wv.w, acc[0][1]))));
      acc[0][2] = fmaf(xv2.x, wv.x, fmaf(xv2.y, wv.y, fmaf(xv2.z, wv.z, fmaf(xv2.w, wv.w, acc[0][2]))));
      acc[0][3] = fmaf(xv3.x, wv.x, fmaf(xv3.y, wv.y, fmaf(xv3.z, wv.z, fmaf(xv3.w, wv.w, acc[0][3]))));
      wv = w1p[k];
      acc[1][0] = fmaf(xv0.x, wv.x, fmaf(xv0.y, wv.y, fmaf(xv0.z, wv.z, fmaf(xv0.w, wv.w, acc[1][0]))));
      acc[1][1] = fmaf(xv1.x, wv.x, fmaf(xv1.y, wv.y, fmaf(xv1.z, wv.z, fmaf(xv1.w, wv.w, acc[1][1]))));
      acc[1][2] = fmaf(xv2.x, wv.x, fmaf(xv2.y, wv.y, fmaf(xv2.z, wv.z, fmaf(xv2.w, wv.w, acc[1][2]))));
      acc[1][3] = fmaf(xv3.x, wv.x, fmaf(xv3.y, wv.y, fmaf(xv3.z, wv.z, fmaf(xv3.w, wv.w, acc[1][3]))));
      wv = w2p[k];
      acc[2][0] = fmaf(xv0.x, wv.x, fmaf(xv0.y, wv.y, fmaf(xv0.z, wv.z, fmaf(xv0.w, wv.w, acc[2][0]))));
      acc[2][1] = fmaf(xv1.x, wv.x, fmaf(xv1.y, wv.y, fmaf(xv1.z, wv.z, fmaf(xv1.w, wv.w, acc[2][1]))));
      acc[2][2] = fmaf(xv2.x, wv.x, fmaf(xv2.y, wv.y, fmaf(xv2.z, wv.z, fmaf(xv2.w, wv.w, acc[2][2]))));
      acc[2][3] = fmaf(xv3.x, wv.x, fmaf(xv3.y, wv.y, fmaf(xv3.z, wv.z, fmaf(xv3.w, wv.w, acc[2][3]))));
    }

    const float b0 = b[t], b1v = b[t + 256];
    const float b2v = has2 ? b[t + 512] : 0.f;
    if (L == 0) {
#pragma unroll
      for (int v = 0; v < 4; ++v) {
        h1s[v][t] = fmaxf(acc[0][v] + b0, 0.f);
        h1s[v][t + 256] = fmaxf(acc[1][v] + b1v, 0.f);
        if (has2) h1s[v][t + 512] = fmaxf(acc[2][v] + b2v, 0.f);
      }
      __syncthreads();
    } else {
#pragma unroll
      for (int v = 0; v < 4; ++v) {
        float* o = out + (size_t)(v0 + v) * NDET;
        o[t] = fmaxf(acc[0][v] + b0, 0.f);
        o[t + 256] = fmaxf(acc[1][v] + b1v, 0.f);
        if (has2) o[t + 512] = fmaxf(acc[2][v] + b2v, 0.f);
      }
    }
  }
}

// ---------------------------------------------------------------------------
// Backprojection: thread-owns-pixel + idx coalesced via LDS staging of
// 72-view chunks. Row pad 77 dwords -> conflict-free LDS reads.
// ---------------------------------------------------------------------------
__global__ __launch_bounds__(256) void backproj_kernel(
    const float* __restrict__ sino, const int* __restrict__ idx,
    float* __restrict__ img) {
  __shared__ int lidx[256 * 77];
  const int t = threadIdx.x;
  const int p_base = blockIdx.x * 256;

  float a0 = 0.f, a1 = 0.f, a2 = 0.f, a3 = 0.f;

#pragma unroll 1
  for (int c = 0; c < 5; ++c) {
    if (c) __syncthreads();
#pragma unroll
    for (int k = 0; k < 18; ++k) {
      const int f = k * 256 + t;
      const int row = f / 18, col4 = f % 18;
      int4 v = *(const int4*)&idx[(size_t)(p_base + row) * VIEWS + c * 72 +
                                  col4 * 4];
      int* dst = &lidx[row * 77 + col4 * 4];
      dst[0] = v.x; dst[1] = v.y; dst[2] = v.z; dst[3] = v.w;
    }
    __syncthreads();
    const int* myrow = &lidx[t * 77];
#pragma unroll
    for (int j = 0; j < 72; j += 4) {
      a0 += sino[myrow[j + 0]];
      a1 += sino[myrow[j + 1]];
      a2 += sino[myrow[j + 2]];
      a3 += sino[myrow[j + 3]];
    }
  }

  const int p = p_base + t;
  const int ix = p >> 9, iy = p & 511;
  img[(NX - 1 - ix) * NY + (NY - 1 - iy)] =
      ((a0 + a1) + (a2 + a3)) * 0.00872665f;  // END_ANGLE / (2*VIEWS)
}

// ---------------------------------------------------------------------------
// fp32 3x3 neighborhood load (zero pad), single plane
// ---------------------------------------------------------------------------
__device__ __forceinline__ void load9(const float* __restrict__ base, int gx,
                                      int gy, float v[9]) {
  const bool xm = gx > 0, xp = gx < NX - 1, ym = gy > 0, yp = gy < NY - 1;
  const float* c = base + gy * NX + gx;
  v[0] = (ym && xm) ? c[-NX - 1] : 0.f;
  v[1] = (ym)       ? c[-NX]     : 0.f;
  v[2] = (ym && xp) ? c[-NX + 1] : 0.f;
  v[3] = (xm)       ? c[-1]      : 0.f;
  v[4] =               c[0];
  v[5] = (xp)       ? c[1]       : 0.f;
  v[6] = (yp && xm) ? c[NX - 1]  : 0.f;
  v[7] = (yp)       ? c[NX]      : 0.f;
  v[8] = (yp && xp) ? c[NX + 1]  : 0.f;
}

__device__ __forceinline__ float dot9(float a, const float v[9],
                                      const float* __restrict__ w) {
  a = fmaf(v[0], w[0], a);
  a = fmaf(v[1], w[1], a);
  a = fmaf(v[2], w[2], a);
  a = fmaf(v[3], w[3], a);
  a = fmaf(v[4], w[4], a);
  a = fmaf(v[5], w[5], a);
  a = fmaf(v[6], w[6], a);
  a = fmaf(v[7], w[7], a);
  a = fmaf(v[8], w[8], a);
  return a;
}

// ---------------------------------------------------------------------------
// conv_in: 1 -> 64 ch, fp32 plane in -> fp32 trunk (yf) + bf16 shadow (ybf).
// Shadow = f2bf(trunk) at write time == R1's staging-time f2bf (bit-identical).
// ---------------------------------------------------------------------------
__global__ __launch_bounds__(256) void conv_in_kernel(
    const float* __restrict__ in, const float* __restrict__ w,
    const float* __restrict__ b, float* __restrict__ outf,
    u16* __restrict__ outb) {
  const int p = blockIdx.x * 256 + threadIdx.x;
  const int gx = p & (NX - 1), gy = p >> 9;
  float v[9];
  load9(in, gx, gy, v);
  float4* of = (float4*)(outf + (size_t)p * 64);
  uint4* ob = (uint4*)(outb + (size_t)p * 64);
#pragma unroll
  for (int oq = 0; oq < 8; ++oq) {
    float f[8];
#pragma unroll
    for (int c = 0; c < 8; ++c)
      f[c] = fmaxf(dot9(b[oq * 8 + c], v, w + (oq * 8 + c) * 9), 0.f);
    of[oq * 2 + 0] = (float4){f[0], f[1], f[2], f[3]};
    of[oq * 2 + 1] = (float4){f[4], f[5], f[6], f[7]};
    uint4 pk;
    pk.x = (unsigned)f2bf(f[0]) | ((unsigned)f2bf(f[1]) << 16);
    pk.y = (unsigned)f2bf(f[2]) | ((unsigned)f2bf(f[3]) << 16);
    pk.z = (unsigned)f2bf(f[4]) | ((unsigned)f2bf(f[5]) << 16);
    pk.w = (unsigned)f2bf(f[6]) | ((unsigned)f2bf(f[7]) << 16);
    ob[oq] = pk;
  }
}

// ---------------------------------------------------------------------------
// Weight prep -> per-(step,mf)-contiguous layout:
//   wR[li][s][mf][lane][j] = W[li][oc=mf*16+(lane&15)][ic=kb*32+(lane>>4)*8+j][tap]
// with s = kb*9 + tap (kb-major).
// ---------------------------------------------------------------------------
__global__ __launch_bounds__(256) void prep_weights_kernel(
    const float* __restrict__ bw1, const float* __restrict__ bw2,
    u16* __restrict__ wR) {
  const int g = blockIdx.x * 256 + threadIdx.x;
  if (g >= 22 * 36864) return;
  const int li = g / 36864, r1 = g % 36864;
  const int s = r1 / 2048, r2 = r1 % 2048;
  const int mf = r2 / 512, r3 = r2 % 512;
  const int lane = r3 / 8, j = r3 % 8;
  const int kb = s / 9, tap = s % 9;  // kb-major step order
  const int kg = lane >> 4, n = lane & 15;
  const int oc = mf * 16 + n;
  const int ic = kb * 32 + kg * 8 + j;
  const float* src = (li < 11) ? bw1 + li * 36864 : bw2 + (li - 11) * 36864;
  wR[g] = f2bf(src[(oc * 64 + ic) * 9 + tap]);
}

// ---------------------------------------------------------------------------
// Staging helpers: bf16 NHWC input, one 32-ch half = 1584 x uint4.
// LOAD issues the 7 global loads into registers (prefetch); WRITE lands them
// in swizzled LDS (compiler inserts the vmcnt waits at first use).
// ---------------------------------------------------------------------------
__device__ __forceinline__ void stage_load(const u16* __restrict__ in_, int xb,
                                           int yb, int tid, int kb,
                                           uint4 p[7]) {
#pragma unroll
  for (int it = 0; it < 7; ++it) {
    const int g = it * 256 + tid;
    uint4 d = {0u, 0u, 0u, 0u};
    if (g < 1584) {
      const int icq = g & 3;
      const int xr = g >> 2;
      const int x66 = xr % 66;
      const int r = xr / 66;
      const int y = yb - 1 + r;
      const int x = xb - 1 + x66;
      if ((unsigned)y < 512u && (unsigned)x < 512u) {
        const size_t gi = ((size_t)((y << 9) + x)) * 64 + kb * 32 + icq * 8;
        d = *(const uint4*)&in_[gi];
      }
    }
    p[it] = d;
  }
}

__device__ __forceinline__ void stage_write(u16* lds, int tid,
                                            const uint4 p[7]) {
#pragma unroll
  for (int it = 0; it < 7; ++it) {
    const int g = it * 256 + tid;
    if (g < 1584) {
      const int icq = g & 3;
      const int xr = g >> 2;
      const int x66 = xr % 66;
      const int slot = icq ^ ((x66 >> 1) & 3);
      *(uint4*)&lds[(xr * 4 + slot) * 8] = p[it];
    }
  }
}

// ---------------------------------------------------------------------------
// One half-K (32 ch) of MFMA work: 9 taps x 16 MFMA.
// ---------------------------------------------------------------------------
__device__ __forceinline__ void compute_half(const u16* lds,
                                             const u16* __restrict__ wA,
                                             int kb, int wv, int lane,
                                             f32x4 acc[4][4]) {
  const int n = lane & 15;
  const int kg = lane >> 4;
#pragma unroll 3
  for (int tap = 0; tap < 9; ++tap) {
    const int s = kb * 9 + tap;
    bf16x8 av[4];
#pragma unroll
    for (int mf = 0; mf < 4; ++mf)
      av[mf] = *(const bf16x8*)&wA[(size_t)s * 2048 + mf * 512 + lane * 8];

    const int r = wv + tap / 3;
    const int dxp1 = tap % 3;

    bf16x8 bfr[4];
#pragma unroll
    for (int nf = 0; nf < 4; ++nf) {
      const int xi = dxp1 + nf * 16 + n;
      const int slot = kg ^ ((xi >> 1) & 3);
      bfr[nf] = *(const bf16x8*)&lds[((r * 66 + xi) * 4 + slot) * 8];
    }
#pragma unroll
    for (int mf = 0; mf < 4; ++mf)
#pragma unroll
      for (int nf = 0; nf < 4; ++nf)
        acc[mf][nf] = __builtin_amdgcn_mfma_f32_16x16x32_bf16(
            av[mf], bfr[nf], acc[mf][nf], 0, 0, 0);
  }
}

// ---------------------------------------------------------------------------
// conv64 MFMA implicit GEMM, bf16 NHWC in. M=64 oc, N=64x*4y, K=576.
// T14 OVERLAP: half-1's global loads are issued into registers BEFORE the
// half-0 compute; the ds_write lands after. Raw `lgkmcnt(0); s_barrier`
// (no vmcnt drain) keeps them in flight across the barrier -> HBM stays
// busy during MFMA (fixes the phase-stall the coop counters exposed:
// MfmaUtil 3.8% / HBM 8.4%, all pipes idle).
// SUB=0: ybf -> zb (bf16). SUB=1: zb -> yf fp32 (+res +relu) AND ybf shadow
// (dual write; shadow = f2bf(trunk) at write == R1 staging f2bf, so the
// whole chain is bit-identical to the 0.0625-passing config).
// ---------------------------------------------------------------------------
template <int SUB>
__global__ __launch_bounds__(256, 4) void conv64_mfma(
    const u16* __restrict__ in_, const u16* __restrict__ wA,
    const float* __restrict__ bias, const float* __restrict__ res,
    void* __restrict__ out_, u16* __restrict__ outs) {
  __shared__ __align__(16) u16 lds[6 * 66 * 32];  // 25,344 B
  const int xb = (blockIdx.x & 7) * 64;
  const int yb = (int)(blockIdx.x >> 3) * 4;
  const int tid = threadIdx.x;
  const int wv = tid >> 6;
  const int lane = tid & 63;
  const int n = lane & 15;
  const int kg = lane >> 4;

  f32x4 acc[4][4];
#pragma unroll
  for (int i = 0; i < 4; ++i)
#pragma unroll
    for (int j = 0; j < 4; ++j) acc[i][j] = (f32x4){0.f, 0.f, 0.f, 0.f};

  uint4 p[7];
  stage_load(in_, xb, yb, tid, 0, p);   // half-0 loads
  stage_write(lds, tid, p);             // (vmcnt waits inserted here)
  stage_load(in_, xb, yb, tid, 1, p);   // PREFETCH half-1 (stays in flight)
  BAR_LDS();                            // half-0 visible; no vmcnt drain
  compute_half(lds, wA, 0, wv, lane, acc);
  BAR_LDS();                            // all half-0 reads done
  stage_write(lds, tid, p);             // land half-1 (vmcnt waits here)
  BAR_LDS();                            // half-1 visible
  compute_half(lds, wA, 1, wv, lane, acc);

  const int y = yb + wv;
#pragma unroll
  for (int mf = 0; mf < 4; ++mf) {
    const float4 bv = *(const float4*)&bias[mf * 16 + kg * 4];
#pragma unroll
    for (int nf = 0; nf < 4; ++nf) {
      const int x = xb + nf * 16 + n;
      const size_t base = ((size_t)((y << 9) + x)) * 64 + mf * 16 + kg * 4;
      float v0 = acc[mf][nf][0] + bv.x;
      float v1 = acc[mf][nf][1] + bv.y;
      float v2 = acc[mf][nf][2] + bv.z;
      float v3 = acc[mf][nf][3] + bv.w;
      if (SUB) {
        float4 rr = *(const float4*)&res[base];
        v0 += rr.x; v1 += rr.y; v2 += rr.z; v3 += rr.w;
        v0 = fmaxf(v0, 0.f); v1 = fmaxf(v1, 0.f);
        v2 = fmaxf(v2, 0.f); v3 = fmaxf(v3, 0.f);
        *(float4*)&((float*)out_)[base] = (float4){v0, v1, v2, v3};
        uint2 pk;
        pk.x = (unsigned)f2bf(v0) | ((unsigned)f2bf(v1) << 16);
        pk.y = (unsigned)f2bf(v2) | ((unsigned)f2bf(v3) << 16);
        *(uint2*)&outs[base] = pk;
      } else {
        v0 = fmaxf(v0, 0.f); v1 = fmaxf(v1, 0.f);
        v2 = fmaxf(v2, 0.f); v3 = fmaxf(v3, 0.f);
        uint2 pk;
        pk.x = (unsigned)f2bf(v0) | ((unsigned)f2bf(v1) << 16);
        pk.y = (unsigned)f2bf(v2) | ((unsigned)f2bf(v3) << 16);
        *(uint2*)&((u16*)out_)[base] = pk;
      }
    }
  }
}

// ---------------------------------------------------------------------------
// conv_out: 64 -> 1, fp32 NHWC trunk in (float4 loads), fp32 plane out.
// ---------------------------------------------------------------------------
__global__ __launch_bounds__(256) void conv_out_kernel(
    const float* __restrict__ in, const float* __restrict__ w,
    const float* __restrict__ b, float* __restrict__ out) {
  const int p = blockIdx.x * 256 + threadIdx.x;
  const int gx = p & (NX - 1), gy = p >> 9;
  float a = b[0];
#pragma unroll
  for (int ty = 0; ty < 3; ++ty) {
#pragma unroll
    for (int tx = 0; tx < 3; ++tx) {
      const int yy = gy + ty - 1, xx = gx + tx - 1;
      if ((unsigned)yy < 512u && (unsigned)xx < 512u) {
        const float4* q = (const float4*)(in + ((size_t)((yy << 9) + xx)) * 64);
        const int tap = ty * 3 + tx;
#pragma unroll
        for (int i = 0; i < 16; ++i) {
          float4 d = q[i];
          a = fmaf(d.x, w[(i * 4 + 0) * 9 + tap], a);
          a = fmaf(d.y, w[(i * 4 + 1) * 9 + tap], a);
          a = fmaf(d.z, w[(i * 4 + 2) * 9 + tap], a);
          a = fmaf(d.w, w[(i * 4 + 3) * 9 + tap], a);
        }
      }
    }
  }
  out[p] = a;
}

// ---------------------------------------------------------------------------
extern "C" void kernel_launch(void* const* d_in, const int* in_sizes, int n_in,
                              void* d_out, int out_size, void* d_ws,
                              size_t ws_size, hipStream_t stream) {
  const float* x      = (const float*)d_in[0];
  const int*   indices= (const int*)d_in[1];
  const float* w1     = (const float*)d_in[2];
  const float* b1     = (const float*)d_in[3];
  const float* w2     = (const float*)d_in[4];
  const float* b2     = (const float*)d_in[5];
  const float* cin_w  = (const float*)d_in[6];
  const float* cin_b  = (const float*)d_in[7];
  const float* bw1    = (const float*)d_in[8];
  const float* bb1    = (const float*)d_in[9];
  const float* bw2    = (const float*)d_in[10];
  const float* bb2    = (const float*)d_in[11];
  const float* cout_w = (const float*)d_in[12];
  const float* cout_b = (const float*)d_in[13];

  float* ws   = (float*)d_ws;
  float* h2   = ws;                        // 360*736 f32
  float* img  = h2 + VIEWS * NDET;         // NPIX f32 (plane)
  float* yf   = img + NPIX;                // 64*NPIX f32 NHWC (exact trunk)
  u16*  ybf   = (u16*)(yf + (size_t)64 * NPIX);  // 64*NPIX bf16 shadow trunk
  u16*  zb    = ybf + (size_t)64 * NPIX;   // 64*NPIX bf16 NHWC (block mid)
  u16*  wAll  = zb + (size_t)64 * NPIX;    // 22*64*576 bf16 (step,mf layout)

  prep_weights_kernel<<<(22 * 36864 + 255) / 256, 256, 0, stream>>>(bw1, bw2,
                                                                    wAll);
  linear2_kernel<<<VIEWS / 4, 256, 0, stream>>>(x, w1, b1, w2, b2, h2);
  backproj_kernel<<<NPIX / 256, 256, 0, stream>>>(h2, indices, img);
  conv_in_kernel<<<NPIX / 256, 256, 0, stream>>>(img, cin_w, cin_b, yf, ybf);

  for (int i = 0; i < 11; ++i) {
    conv64_mfma<0><<<1024, 256, 0, stream>>>(
        ybf, wAll + i * 36864, bb1 + i * 64, nullptr, zb, nullptr);
    conv64_mfma<1><<<1024, 256, 0, stream>>>(
        zb, wAll + (11 + i) * 36864, bb2 + i * 64, yf, yf, ybf);
  }
  conv_out_kernel<<<NPIX / 256, 256, 0, stream>>>(yf, cout_w, cout_b,
                                                  (float*)d_out);
}

// Round 9
// 1870.658 us; speedup vs baseline: 2.1267x; 1.0450x over previous
//
#include <hip/hip_runtime.h>

#define VIEWS 360
#define NDET 736
#define NX 512
#define NY 512
#define NPIX (NX * NY)

typedef unsigned short u16;
typedef __attribute__((ext_vector_type(8))) short bf16x8;
typedef __attribute__((ext_vector_type(4))) float f32x4;

__device__ __forceinline__ u16 f2bf(float f) {
  unsigned u = __float_as_uint(f);
  return (u16)((u + 0x7fffu + ((u >> 16) & 1u)) >> 16);
}

// async 16-B global -> LDS DMA (gfx950). LDS dest = wave-uniform base +
// lane*16 (m104); source address is per-lane. R3-proven on this problem.
__device__ __forceinline__ void gload_lds16(const void* g, void* l) {
  __builtin_amdgcn_global_load_lds(
      (const __attribute__((address_space(1))) void*)g,
      (__attribute__((address_space(3))) void*)l, 16, 0, 0);
}

// ---------------------------------------------------------------------------
// Linear layer (R1 champion version): out[v,d] = relu(b[d] + sum_k in[v,k]*w[d,k])
// ---------------------------------------------------------------------------
__global__ __launch_bounds__(256) void linear_relu_kernel(
    const float* __restrict__ in, const float* __restrict__ w,
    const float* __restrict__ b, float* __restrict__ out) {
  __shared__ __align__(16) float xin[NDET];
  const int v = blockIdx.x;
  const float4* src4 = (const float4*)(in + v * NDET);
  float4* dst4 = (float4*)xin;
  for (int k = threadIdx.x; k < NDET / 4; k += 256) dst4[k] = src4[k];
  __syncthreads();

  for (int d = threadIdx.x; d < NDET; d += 256) {
    const float4* w4 = (const float4*)(w + d * NDET);
    float acc = 0.f;
#pragma unroll 8
    for (int k = 0; k < NDET / 4; ++k) {
      float4 xv = ((const float4*)xin)[k];
      float4 wv = w4[k];
      acc = fmaf(xv.x, wv.x, acc);
      acc = fmaf(xv.y, wv.y, acc);
      acc = fmaf(xv.z, wv.z, acc);
      acc = fmaf(xv.w, wv.w, acc);
    }
    out[v * NDET + d] = fmaxf(acc + b[d], 0.f);
  }
}

// ---------------------------------------------------------------------------
// Backprojection (R1 champion version).
// ---------------------------------------------------------------------------
__global__ __launch_bounds__(256) void backproj_kernel(
    const float* __restrict__ sino, const int* __restrict__ idx,
    float* __restrict__ img) {
  __shared__ int lidx[256 * 77];
  const int t = threadIdx.x;
  const int p_base = blockIdx.x * 256;

  float a0 = 0.f, a1 = 0.f, a2 = 0.f, a3 = 0.f;

#pragma unroll 1
  for (int c = 0; c < 5; ++c) {
    if (c) __syncthreads();
#pragma unroll
    for (int k = 0; k < 18; ++k) {
      const int f = k * 256 + t;
      const int row = f / 18, col4 = f % 18;
      int4 v = *(const int4*)&idx[(size_t)(p_base + row) * VIEWS + c * 72 +
                                  col4 * 4];
      int* dst = &lidx[row * 77 + col4 * 4];
      dst[0] = v.x; dst[1] = v.y; dst[2] = v.z; dst[3] = v.w;
    }
    __syncthreads();
    const int* myrow = &lidx[t * 77];
#pragma unroll
    for (int j = 0; j < 72; j += 4) {
      a0 += sino[myrow[j + 0]];
      a1 += sino[myrow[j + 1]];
      a2 += sino[myrow[j + 2]];
      a3 += sino[myrow[j + 3]];
    }
  }

  const int p = p_base + t;
  const int ix = p >> 9, iy = p & 511;
  img[(NX - 1 - ix) * NY + (NY - 1 - iy)] =
      ((a0 + a1) + (a2 + a3)) * 0.00872665f;  // END_ANGLE / (2*VIEWS)
}

// ---------------------------------------------------------------------------
// fp32 3x3 neighborhood load (zero pad), single plane
// ---------------------------------------------------------------------------
__device__ __forceinline__ void load9(const float* __restrict__ base, int gx,
                                      int gy, float v[9]) {
  const bool xm = gx > 0, xp = gx < NX - 1, ym = gy > 0, yp = gy < NY - 1;
  const float* c = base + gy * NX + gx;
  v[0] = (ym && xm) ? c[-NX - 1] : 0.f;
  v[1] = (ym)       ? c[-NX]     : 0.f;
  v[2] = (ym && xp) ? c[-NX + 1] : 0.f;
  v[3] = (xm)       ? c[-1]      : 0.f;
  v[4] =               c[0];
  v[5] = (xp)       ? c[1]       : 0.f;
  v[6] = (yp && xm) ? c[NX - 1]  : 0.f;
  v[7] = (yp)       ? c[NX]      : 0.f;
  v[8] = (yp && xp) ? c[NX + 1]  : 0.f;
}

__device__ __forceinline__ float dot9(float a, const float v[9],
                                      const float* __restrict__ w) {
  a = fmaf(v[0], w[0], a);
  a = fmaf(v[1], w[1], a);
  a = fmaf(v[2], w[2], a);
  a = fmaf(v[3], w[3], a);
  a = fmaf(v[4], w[4], a);
  a = fmaf(v[5], w[5], a);
  a = fmaf(v[6], w[6], a);
  a = fmaf(v[7], w[7], a);
  a = fmaf(v[8], w[8], a);
  return a;
}

// ---------------------------------------------------------------------------
// conv_in (R1): 1 -> 64 channels, fp32 plane in -> fp32 NHWC out.
// ---------------------------------------------------------------------------
__global__ __launch_bounds__(256) void conv_in_kernel(
    const float* __restrict__ in, const float* __restrict__ w,
    const float* __restrict__ b, float* __restrict__ out) {
  const int p = blockIdx.x * 256 + threadIdx.x;
  const int gx = p & (NX - 1), gy = p >> 9;
  float v[9];
  load9(in, gx, gy, v);
  float4* o = (float4*)(out + (size_t)p * 64);
#pragma unroll
  for (int oq = 0; oq < 16; ++oq) {
    float4 r;
    r.x = fmaxf(dot9(b[oq * 4 + 0], v, w + (oq * 4 + 0) * 9), 0.f);
    r.y = fmaxf(dot9(b[oq * 4 + 1], v, w + (oq * 4 + 1) * 9), 0.f);
    r.z = fmaxf(dot9(b[oq * 4 + 2], v, w + (oq * 4 + 2) * 9), 0.f);
    r.w = fmaxf(dot9(b[oq * 4 + 3], v, w + (oq * 4 + 3) * 9), 0.f);
    o[oq] = r;
  }
}

// ---------------------------------------------------------------------------
// Weight prep (R1 layout): wR[li][s][lane][mf][j], s = kb*9 + tap.
// Also zeroes a 32-u16 pad after wR (OOB source for conv64_pipe staging).
// ---------------------------------------------------------------------------
__global__ __launch_bounds__(256) void prep_weights_kernel(
    const float* __restrict__ bw1, const float* __restrict__ bw2,
    u16* __restrict__ wR) {
  const int g = blockIdx.x * 256 + threadIdx.x;
  if (g >= 22 * 36864) return;
  if (g < 32) wR[22 * 36864 + g] = 0;  // zero pad for OOB staging
  const int li = g / 36864, r1 = g % 36864;
  const int s = r1 / 2048, r2 = r1 % 2048;
  const int lane = r2 / 32, r3 = r2 % 32;
  const int mf = r3 / 8, j = r3 % 8;
  const int kb = s / 9, tap = s % 9;  // kb-major step order
  const int kg = lane >> 4, n = lane & 15;
  const int oc = mf * 16 + n;
  const int ic = kb * 32 + kg * 8 + j;
  const float* src = (li < 11) ? bw1 + li * 36864 : bw2 + (li - 11) * 36864;
  wR[g] = f2bf(src[(oc * 64 + ic) * 9 + tap]);
}

// ---------------------------------------------------------------------------
// Shared MFMA inner: one 32-ch half (9 taps x 16 MFMA). A-index = R1 layout.
// ---------------------------------------------------------------------------
__device__ __forceinline__ void compute_half(const u16* lds,
                                             const u16* __restrict__ wA,
                                             int kb, int wv, int lane,
                                             f32x4 acc[4][4]) {
  const int n = lane & 15;
  const int kg = lane >> 4;
#pragma unroll 3
  for (int tap = 0; tap < 9; ++tap) {
    const int s = kb * 9 + tap;
    bf16x8 av[4];
#pragma unroll
    for (int mf = 0; mf < 4; ++mf)
      av[mf] = *(const bf16x8*)&wA[((size_t)s * 64 + lane) * 32 + mf * 8];

    const int r = wv + tap / 3;
    const int dxp1 = tap % 3;

    bf16x8 bfr[4];
#pragma unroll
    for (int nf = 0; nf < 4; ++nf) {
      const int xi = dxp1 + nf * 16 + n;
      const int slot = kg ^ ((xi >> 1) & 3);
      bfr[nf] = *(const bf16x8*)&lds[((r * 66 + xi) * 4 + slot) * 8];
    }
#pragma unroll
    for (int mf = 0; mf < 4; ++mf)
#pragma unroll
      for (int nf = 0; nf < 4; ++nf)
        acc[mf][nf] = __builtin_amdgcn_mfma_f32_16x16x32_bf16(
            av[mf], bfr[nf], acc[mf][nf], 0, 0, 0);
  }
}

// ---------------------------------------------------------------------------
// conv1 (R1 champion, verbatim semantics): fp32 yf in -> bf16 zb out.
// K-split single-buffer staging, 25.3 KB LDS, 4 blocks/CU.
// ---------------------------------------------------------------------------
__global__ __launch_bounds__(256, 4) void conv64_c1(
    const float* __restrict__ in_, const u16* __restrict__ wA,
    const float* __restrict__ bias, u16* __restrict__ out_) {
  __shared__ __align__(16) u16 lds[6 * 66 * 32];  // 25,344 B
  const int xb = (blockIdx.x & 7) * 64;
  const int yb = (int)(blockIdx.x >> 3) * 4;
  const int tid = threadIdx.x;
  const int wv = tid >> 6;
  const int lane = tid & 63;
  const int n = lane & 15;
  const int kg = lane >> 4;

  f32x4 acc[4][4];
#pragma unroll
  for (int i = 0; i < 4; ++i)
#pragma unroll
    for (int j = 0; j < 4; ++j) acc[i][j] = (f32x4){0.f, 0.f, 0.f, 0.f};

#pragma unroll 1
  for (int kb = 0; kb < 2; ++kb) {
    if (kb) __syncthreads();
#pragma unroll
    for (int it = 0; it < 7; ++it) {
      const int g = it * 256 + tid;
      if (g < 1584) {
        const int icq = g & 3;
        const int xr = g >> 2;
        const int x66 = xr % 66;
        const int r = xr / 66;
        const int y = yb - 1 + r;
        const int x = xb - 1 + x66;
        uint4 d = {0u, 0u, 0u, 0u};
        if ((unsigned)y < 512u && (unsigned)x < 512u) {
          const size_t gi = ((size_t)((y << 9) + x)) * 64 + kb * 32 + icq * 8;
          const float* s = &in_[gi];
          float4 f0 = *(const float4*)s;
          float4 f1 = *(const float4*)(s + 4);
          d.x = (unsigned)f2bf(f0.x) | ((unsigned)f2bf(f0.y) << 16);
          d.y = (unsigned)f2bf(f0.z) | ((unsigned)f2bf(f0.w) << 16);
          d.z = (unsigned)f2bf(f1.x) | ((unsigned)f2bf(f1.y) << 16);
          d.w = (unsigned)f2bf(f1.z) | ((unsigned)f2bf(f1.w) << 16);
        }
        const int slot = icq ^ ((x66 >> 1) & 3);
        *(uint4*)&lds[(xr * 4 + slot) * 8] = d;
      }
    }
    __syncthreads();
    compute_half(lds, wA, kb, wv, lane, acc);
  }

  const int y = yb + wv;
#pragma unroll
  for (int mf = 0; mf < 4; ++mf) {
    const float4 bv = *(const float4*)&bias[mf * 16 + kg * 4];
#pragma unroll
    for (int nf = 0; nf < 4; ++nf) {
      const int x = xb + nf * 16 + n;
      const size_t base = ((size_t)((y << 9) + x)) * 64 + mf * 16 + kg * 4;
      float v0 = fmaxf(acc[mf][nf][0] + bv.x, 0.f);
      float v1 = fmaxf(acc[mf][nf][1] + bv.y, 0.f);
      float v2 = fmaxf(acc[mf][nf][2] + bv.z, 0.f);
      float v3 = fmaxf(acc[mf][nf][3] + bv.w, 0.f);
      uint2 pk;
      pk.x = (unsigned)f2bf(v0) | ((unsigned)f2bf(v1) << 16);
      pk.y = (unsigned)f2bf(v2) | ((unsigned)f2bf(v3) << 16);
      *(uint2*)&out_[base] = pk;
    }
  }
}

// ---------------------------------------------------------------------------
// conv2 PIPELINED (the round's single change): bf16 zb in -> fp32 yf (+res).
// Depth-2 T3/T4 pipeline: ALL 14 per-thread global_load_lds (both halves,
// double-buffered LDS 2x25.3KB) issued up front; counted vmcnt(6) waits for
// half-0 only -> half-1 keeps landing under compute_half(0)'s MFMAs; vmcnt(0)
// before half 1. Zero staging VGPRs (no R8-style spill). Source-swizzled,
// linear LDS dest (rule #21; R3-refcheck-proven pattern). OOB lanes read a
// zeroed pad. Raw s_barrier (no vmcnt drain) + sched_barrier (rule #18).
// LDS 50.7KB -> 3 blocks/CU.
// ---------------------------------------------------------------------------
__global__ __launch_bounds__(256, 3) void conv64_pipe(
    const u16* __restrict__ in_, const u16* __restrict__ wA,
    const float* __restrict__ bias, const float* __restrict__ res,
    float* __restrict__ out_, const u16* __restrict__ zpad) {
  __shared__ __align__(16) u16 lds[2][6 * 66 * 32];  // 50,688 B
  const int xb = (blockIdx.x & 7) * 64;
  const int yb = (int)(blockIdx.x >> 3) * 4;
  const int tid = threadIdx.x;
  const int wv = tid >> 6;
  const int lane = tid & 63;
  const int n = lane & 15;
  const int kg = lane >> 4;

  // issue ALL staging (both halves) asynchronously, up front
#pragma unroll
  for (int kb = 0; kb < 2; ++kb) {
#pragma unroll
    for (int it = 0; it < 7; ++it) {
      const int g = it * 256 + tid;
      if (g < 1584) {
        const int j = g & 3;          // linear LDS slot
        const int xr = g >> 2;
        const int x66 = xr % 66;
        const int r = xr / 66;
        const int y = yb - 1 + r;
        const int x = xb - 1 + x66;
        const int icq = j ^ ((x66 >> 1) & 3);  // pre-swizzled source chunk
        const u16* src = zpad;
        if ((unsigned)y < 512u && (unsigned)x < 512u)
          src = in_ + ((size_t)((y << 9) + x)) * 64 + kb * 32 + icq * 8;
        gload_lds16(src, &lds[kb][(size_t)(g & ~63) * 8]);
      }
    }
  }

  f32x4 acc[4][4];
#pragma unroll
  for (int i = 0; i < 4; ++i)
#pragma unroll
    for (int j = 0; j < 4; ++j) acc[i][j] = (f32x4){0.f, 0.f, 0.f, 0.f};

  // half-0 ready (6 oldest per wave = its half-0 loads); half-1 in flight
  asm volatile("s_waitcnt vmcnt(6)\n\ts_barrier" ::: "memory");
  __builtin_amdgcn_sched_barrier(0);
  compute_half(lds[0], wA, 0, wv, lane, acc);

  // all loads landed
  asm volatile("s_waitcnt vmcnt(0)\n\ts_barrier" ::: "memory");
  __builtin_amdgcn_sched_barrier(0);
  compute_half(lds[1], wA, 1, wv, lane, acc);

  const int y = yb + wv;
#pragma unroll
  for (int mf = 0; mf < 4; ++mf) {
    const float4 bv = *(const float4*)&bias[mf * 16 + kg * 4];
#pragma unroll
    for (int nf = 0; nf < 4; ++nf) {
      const int x = xb + nf * 16 + n;
      const size_t base = ((size_t)((y << 9) + x)) * 64 + mf * 16 + kg * 4;
      float4 rr = *(const float4*)&res[base];
      float v0 = fmaxf(acc[mf][nf][0] + bv.x + rr.x, 0.f);
      float v1 = fmaxf(acc[mf][nf][1] + bv.y + rr.y, 0.f);
      float v2 = fmaxf(acc[mf][nf][2] + bv.z + rr.z, 0.f);
      float v3 = fmaxf(acc[mf][nf][3] + bv.w + rr.w, 0.f);
      *(float4*)&out_[base] = (float4){v0, v1, v2, v3};
    }
  }
}

// ---------------------------------------------------------------------------
// conv_out (R1): 64 -> 1, fp32 NHWC in, fp32 plane out.
// ---------------------------------------------------------------------------
__global__ __launch_bounds__(256) void conv_out_kernel(
    const float* __restrict__ in, const float* __restrict__ w,
    const float* __restrict__ b, float* __restrict__ out) {
  const int p = blockIdx.x * 256 + threadIdx.x;
  const int gx = p & (NX - 1), gy = p >> 9;
  float a = b[0];
#pragma unroll
  for (int ty = 0; ty < 3; ++ty) {
#pragma unroll
    for (int tx = 0; tx < 3; ++tx) {
      const int yy = gy + ty - 1, xx = gx + tx - 1;
      if ((unsigned)yy < 512u && (unsigned)xx < 512u) {
        const float4* q = (const float4*)(in + ((size_t)((yy << 9) + xx)) * 64);
        const int tap = ty * 3 + tx;
#pragma unroll
        for (int i = 0; i < 16; ++i) {
          float4 d = q[i];
          a = fmaf(d.x, w[(i * 4 + 0) * 9 + tap], a);
          a = fmaf(d.y, w[(i * 4 + 1) * 9 + tap], a);
          a = fmaf(d.z, w[(i * 4 + 2) * 9 + tap], a);
          a = fmaf(d.w, w[(i * 4 + 3) * 9 + tap], a);
        }
      }
    }
  }
  out[p] = a;
}

// ---------------------------------------------------------------------------
extern "C" void kernel_launch(void* const* d_in, const int* in_sizes, int n_in,
                              void* d_out, int out_size, void* d_ws,
                              size_t ws_size, hipStream_t stream) {
  const float* x      = (const float*)d_in[0];
  const int*   indices= (const int*)d_in[1];
  const float* w1     = (const float*)d_in[2];
  const float* b1     = (const float*)d_in[3];
  const float* w2     = (const float*)d_in[4];
  const float* b2     = (const float*)d_in[5];
  const float* cin_w  = (const float*)d_in[6];
  const float* cin_b  = (const float*)d_in[7];
  const float* bw1    = (const float*)d_in[8];
  const float* bb1    = (const float*)d_in[9];
  const float* bw2    = (const float*)d_in[10];
  const float* bb2    = (const float*)d_in[11];
  const float* cout_w = (const float*)d_in[12];
  const float* cout_b = (const float*)d_in[13];

  float* ws   = (float*)d_ws;
  float* h1   = ws;                      // 360*736 f32
  float* h2   = h1 + VIEWS * NDET;       // 360*736 f32
  float* img  = h2 + VIEWS * NDET;       // NPIX f32 (plane)
  float* yf   = img + NPIX;              // 64*NPIX f32 NHWC (residual stream)
  u16*  zb    = (u16*)(yf + (size_t)64 * NPIX);  // 64*NPIX bf16 NHWC
  u16*  wAll  = zb + (size_t)64 * NPIX;  // 22*64*576 bf16 (R1 step layout)
  u16*  zpad  = wAll + 22 * 36864;       // 32 u16 of zeros (OOB source)

  prep_weights_kernel<<<(22 * 36864 + 255) / 256, 256, 0, stream>>>(bw1, bw2,
                                                                    wAll);
  linear_relu_kernel<<<VIEWS, 256, 0, stream>>>(x, w1, b1, h1);
  linear_relu_kernel<<<VIEWS, 256, 0, stream>>>(h1, w2, b2, h2);
  backproj_kernel<<<NPIX / 256, 256, 0, stream>>>(h2, indices, img);
  conv_in_kernel<<<NPIX / 256, 256, 0, stream>>>(img, cin_w, cin_b, yf);

  for (int i = 0; i < 11; ++i) {
    conv64_c1<<<1024, 256, 0, stream>>>(yf, wAll + i * 36864, bb1 + i * 64,
                                        zb);
    conv64_pipe<<<1024, 256, 0, stream>>>(zb, wAll + (11 + i) * 36864,
                                          bb2 + i * 64, yf, yf, zpad);
  }
  conv_out_kernel<<<NPIX / 256, 256, 0, stream>>>(yf, cout_w, cout_b,
                                                  (float*)d_out);
}